// Round 5
// baseline (413.427 us; speedup 1.0000x reference)
//
#include <hip/hip_runtime.h>
#include <stdint.h>

// Problem constants
#define L_SEQ 2048
#define BATCH 2
#define DIM   1024
#define NH    16
#define HDIM  64
#define DFF_  4096
#define ROWS  (L_SEQ*BATCH)   // 4096 token rows, row index = l*BATCH + b

// softmax scale folded into Q at split time: (1/sqrt(64)) * log2(e)
#define QSCALE 0.18033688011112042f

typedef __attribute__((ext_vector_type(8))) short  bf16x8;
typedef __attribute__((ext_vector_type(4))) float  floatx4;

__device__ __forceinline__ unsigned short f2bf(float f) {
    union { float f; uint32_t u; } x; x.f = f;
    uint32_t r = x.u + 0x7fffu + ((x.u >> 16) & 1u);   // RNE
    return (unsigned short)(r >> 16);
}
__device__ __forceinline__ float bf2f(unsigned short b) {
    union { uint32_t u; float f; } x; x.u = ((uint32_t)b) << 16;
    return x.f;
}
__device__ __forceinline__ uint32_t fbits(float f) {
    union { float f; uint32_t u; } x; x.f = f; return x.u;
}

// async global->LDS, 16B per lane; lds dest = wave-uniform base + lane*16
__device__ __forceinline__ void load_lds16(const unsigned short* g, unsigned short* l) {
    __builtin_amdgcn_global_load_lds(
        (const __attribute__((address_space(1))) unsigned int*)g,
        (__attribute__((address_space(3))) unsigned int*)l, 16, 0, 0);
}

// ---------------------------------------------------------------------------
// All 4 weight transposes in one kernel: fp32 [K,N] -> bf16 [N,K], 32x32 tiles
// ---------------------------------------------------------------------------
__global__ __launch_bounds__(256)
void transpose_all(const float* __restrict__ s0, unsigned short* __restrict__ d0,
                   const float* __restrict__ s1, unsigned short* __restrict__ d1,
                   const float* __restrict__ s2, unsigned short* __restrict__ d2,
                   const float* __restrict__ s3, unsigned short* __restrict__ d3)
{
    const int id = blockIdx.x;
    const float* src; unsigned short* dst; int K, N, local;
    if (id < 3072)      { src = s0; dst = d0; K = 1024; N = 3072; local = id; }
    else if (id < 4096) { src = s1; dst = d1; K = 1024; N = 1024; local = id - 3072; }
    else if (id < 8192) { src = s2; dst = d2; K = 1024; N = 4096; local = id - 4096; }
    else                { src = s3; dst = d3; K = 4096; N = 1024; local = id - 8192; }
    const int nN = N >> 5;
    const int bk = (local / nN) * 32, bn = (local % nN) * 32;

    __shared__ float tile[32][36];
    const int t = threadIdx.x;
    const int r = t >> 3, c4 = (t & 7) * 4;
    *(float4*)&tile[r][c4] = *(const float4*)(src + (size_t)(bk + r) * N + bn + c4);
    __syncthreads();
    ushort4 o;
    o.x = f2bf(tile[c4 + 0][r]);
    o.y = f2bf(tile[c4 + 1][r]);
    o.z = f2bf(tile[c4 + 2][r]);
    o.w = f2bf(tile[c4 + 3][r]);
    *(ushort4*)(dst + (size_t)(bn + r) * K + bk + c4) = o;
}

// ---------------------------------------------------------------------------
// LayerNorm: [4096,1024] fp32 or bf16 input -> bf16 out, one block per row
// ---------------------------------------------------------------------------
template<int INBF16>
__global__ __launch_bounds__(256)
void ln_rows(const void* __restrict__ xin, const float* __restrict__ g,
             const float* __restrict__ bta, unsigned short* __restrict__ out)
{
    const int row = blockIdx.x;
    const int t = threadIdx.x;
    float4 v;
    if (INBF16) {
        const ushort4 u = ((const ushort4*)((const unsigned short*)xin + (size_t)row * DIM))[t];
        v.x = bf2f(u.x); v.y = bf2f(u.y); v.z = bf2f(u.z); v.w = bf2f(u.w);
    } else {
        v = ((const float4*)((const float*)xin + (size_t)row * DIM))[t];
    }
    float s  = v.x + v.y + v.z + v.w;
    float s2 = v.x*v.x + v.y*v.y + v.z*v.z + v.w*v.w;
#pragma unroll
    for (int d = 1; d < 64; d <<= 1) { s += __shfl_xor(s, d, 64); s2 += __shfl_xor(s2, d, 64); }
    __shared__ float ss[4], ss2[4];
    const int w = t >> 6, lane = t & 63;
    if (lane == 0) { ss[w] = s; ss2[w] = s2; }
    __syncthreads();
    s  = ss[0] + ss[1] + ss[2] + ss[3];
    s2 = ss2[0] + ss2[1] + ss2[2] + ss2[3];
    const float mu   = s * (1.0f / DIM);
    const float var  = s2 * (1.0f / DIM) - mu * mu;
    const float rstd = rsqrtf(var + 1e-5f);
    const float4 gv = ((const float4*)g)[t];
    const float4 bv = ((const float4*)bta)[t];
    ushort4 o;
    o.x = f2bf((v.x - mu) * rstd * gv.x + bv.x);
    o.y = f2bf((v.y - mu) * rstd * gv.y + bv.y);
    o.z = f2bf((v.z - mu) * rstd * gv.z + bv.z);
    o.w = f2bf((v.w - mu) * rstd * gv.w + bv.w);
    *(ushort4*)(out + (size_t)row * DIM + t * 4) = o;
}

// ---------------------------------------------------------------------------
// bf16 GEMM, B^T input (Bt [N,K]); C = A@B + bias (+resid) (gelu?)
// MI=4: 128x128 tile; MI=2: 64x128 tile. BK=32, m97 structure.
// RESID: 0=none, 1=fp32, 2=bf16
// SPLITK>1: blockIdx.z = K-slice; kz>0 writes raw fp32 partial.
// ---------------------------------------------------------------------------
template<int GELU, int RESID, int OUTBF16, int MI, int SPLITK>
__global__ __launch_bounds__(256)
void gemm_bt(const unsigned short* __restrict__ A,   // [M,K] bf16
             const unsigned short* __restrict__ Bt,  // [N,K] bf16
             const float* __restrict__ bias,         // [N]
             const void* __restrict__ resid,         // [M,N] fp32/bf16 or null
             void* __restrict__ outp,                // bf16 or fp32 [M,N]
             float* __restrict__ part,               // fp32 partials (SPLITK>1)
             int M, int N, int K)
{
    __shared__ unsigned short As[MI * 32 * 32];   // flat, unpadded
    __shared__ unsigned short Bs[128 * 32];
    const int t = threadIdx.x;
    const int w = t >> 6, lane = t & 63;
    const int quad = lane >> 4, l16 = lane & 15;
    const int wm = (w >> 1) * (MI * 16), wn = (w & 1) * 64;
    const int bm = blockIdx.x * (MI * 32), bn = blockIdx.y * 128;

    const int srow = lane >> 2;
    const int scol = (lane & 3) * 8;

    const unsigned short* Ab = A  + (size_t)bm * K;
    const unsigned short* Bb = Bt + (size_t)bn * K;

    floatx4 acc[MI][4] = {};

    const int kspan = (SPLITK > 1) ? (K / SPLITK) : K;
    const int k0    = (SPLITK > 1) ? blockIdx.z * kspan : 0;

    for (int kc = k0; kc < k0 + kspan; kc += 32) {
        __syncthreads();
#pragma unroll
        for (int i = 0; i < MI / 2; ++i) {
            const int r0 = (i * 4 + w) * 16;
            load_lds16(Ab + (size_t)(r0 + srow) * K + kc + scol, As + r0 * 32);
        }
#pragma unroll
        for (int i = 0; i < 2; ++i) {
            const int r0 = (i * 4 + w) * 16;
            load_lds16(Bb + (size_t)(r0 + srow) * K + kc + scol, Bs + r0 * 32);
        }
        __syncthreads();
        bf16x8 af[MI], bf[4];
#pragma unroll
        for (int i = 0; i < MI; ++i) af[i] = *(const bf16x8*)(As + (wm + i*16 + l16) * 32 + quad * 8);
#pragma unroll
        for (int j = 0; j < 4; ++j) bf[j] = *(const bf16x8*)(Bs + (wn + j*16 + l16) * 32 + quad * 8);
#pragma unroll
        for (int i = 0; i < MI; ++i)
#pragma unroll
            for (int j = 0; j < 4; ++j)
                acc[i][j] = __builtin_amdgcn_mfma_f32_16x16x32_bf16(af[i], bf[j], acc[i][j], 0, 0, 0);
    }

    if (SPLITK > 1 && blockIdx.z > 0) {
        float* po = part + (size_t)(blockIdx.z - 1) * ((size_t)M * N);
#pragma unroll
        for (int i = 0; i < MI; ++i)
#pragma unroll
            for (int j = 0; j < 4; ++j) {
                const int col = bn + wn + j*16 + l16;
#pragma unroll
                for (int r = 0; r < 4; ++r) {
                    const int row = bm + wm + i*16 + quad*4 + r;
                    po[(size_t)row * N + col] = acc[i][j][r];
                }
            }
        return;
    }

#pragma unroll
    for (int i = 0; i < MI; ++i) {
#pragma unroll
        for (int j = 0; j < 4; ++j) {
            const int col = bn + wn + j*16 + l16;
            const float bv = bias[col];
#pragma unroll
            for (int r = 0; r < 4; ++r) {
                const int row = bm + wm + i*16 + quad*4 + r;
                float v = acc[i][j][r] + bv;
                if (RESID == 1) v += ((const float*)resid)[(size_t)row * N + col];
                if (RESID == 2) v += bf2f(((const unsigned short*)resid)[(size_t)row * N + col]);
                if (GELU) {
                    const float u = v;
                    float c = 2.302204225929898f * (u + 0.044715f * u * u * u);
                    c = fminf(c, 80.f);
                    const float e = exp2f(c);
                    v = u * (e / (1.0f + e));
                }
                if (OUTBF16) ((unsigned short*)outp)[(size_t)row * N + col] = f2bf(v);
                else         ((float*)outp)[(size_t)row * N + col] = v;
            }
        }
    }
}

// ---------------------------------------------------------------------------
// 256x256-tile deep-pipelined GEMM v2, BK=32, 64 KiB STATIC LDS.
// (unchanged from R4 — verified: bank-conflict 0, out of top-5)
// ---------------------------------------------------------------------------
#define SWZ32(p) ((p) ^ ((((p) >> 7) & 3) << 4))

template<int GELU, int RESID, int OUTBF16, int SPLITK>
__global__ __launch_bounds__(512, 2)
void gemm256b(const unsigned short* __restrict__ A,   // [M,K] bf16
              const unsigned short* __restrict__ Bt,  // [N,K] bf16
              const float* __restrict__ bias,         // [N]
              const void* __restrict__ resid,         // [M,N] or null
              void* __restrict__ outp,                // bf16 or fp32 [M,N]
              float* __restrict__ part,               // fp32 partials
              int M, int N, int K, int nbx)
{
    __shared__ unsigned short lds[32768];            // 64 KiB exactly
    const int t = threadIdx.x;
    const int w = t >> 6, lane = t & 63;
    const int quad = lane >> 4, l16 = lane & 15;
    const int wr = w >> 2, wc = w & 3;

    // bijective XCD swizzle (gridDim.x % 8 == 0)
    const int nwg = gridDim.x;
    const int cpx = nwg >> 3;
    const int bid = (blockIdx.x & 7) * cpx + (blockIdx.x >> 3);
    const int bm = (bid % nbx) * 256, bn = (bid / nbx) * 256;

    const unsigned short* Ab = A  + (size_t)bm * K;
    const unsigned short* Bb = Bt + (size_t)bn * K;

    // staging source offsets for an 8KB half staged at half-local byte t*16
    const int sh   = SWZ32(t * 16);          // [0,8192)
    const int rp0  = sh >> 6;                // swizzled row within half [0,128)
    const int colE = (sh & 63) >> 1;         // element col within BK=32
    const int w0 = rp0 & 63, hb = rp0 >> 6;  // band-within / band-half bit
    // B: linear rows per half
    const size_t bOff0 = (size_t)rp0 * K + colE;
    const size_t bOff1 = (size_t)(128 + rp0) * K + colE;
    // A: band-permuted rows
    const size_t aOff0 = (size_t)(w0 + hb * 128)      * K + colE;  // bands 0,1
    const size_t aOff1 = (size_t)(w0 + hb * 128 + 64) * K + colE;  // bands 2,3

#define STGH(dstE_, srcp_, kta_, off_) \
    load_lds16((srcp_) + (size_t)(kta_) * 32 + (off_), lds + (dstE_) + w * 512)
#define BARF    do { __builtin_amdgcn_s_barrier(); asm volatile("" ::: "memory"); } while (0)
#define CL_PRE  do { asm volatile("s_waitcnt lgkmcnt(0)" ::: "memory");    \
                     __builtin_amdgcn_sched_barrier(0);                    \
                     __builtin_amdgcn_s_setprio(1); } while (0)
#define CL_POST do { __builtin_amdgcn_s_setprio(0);                        \
                     __builtin_amdgcn_sched_barrier(0); } while (0)

    floatx4 acc[8][4] = {};
    const int nt  = ((SPLITK > 1) ? (K / SPLITK) : K) >> 5;
    const int ktb = (SPLITK > 1) ? blockIdx.y * nt : 0;

    // prologue: tiles 0,1 fully staged; wait tile0
    STGH(0,     Ab, ktb,     aOff0);  STGH(4096,  Ab, ktb,     aOff1);
    STGH(8192,  Bb, ktb,     bOff0);  STGH(12288, Bb, ktb,     bOff1);
    STGH(16384, Ab, ktb + 1, aOff0);  STGH(20480, Ab, ktb + 1, aOff1);
    STGH(24576, Bb, ktb + 1, bOff0);  STGH(28672, Bb, ktb + 1, bOff1);
    asm volatile("s_waitcnt vmcnt(4)" ::: "memory");
    BARF;

    for (int i = 0; i < nt; ++i) {
        const int cb = i & 1;
        const int i1 = (i + 1 < nt) ? i + 1 : nt - 1;
        const int i2 = (i + 2 < nt) ? i + 2 : nt - 1;
        const int oA = cb * 16384, oB = oA + 8192;
        const int xA = (cb ^ 1) * 16384;
        const char* Abase = (const char*)lds + cb * 32768;
        const char* Bbase = Abase + 16384;
        bf16x8 af[4], bf[4];

        // ---- P0: stage A(i+1)-P1half -> other buf; read af-P0band + bf-all ----
        STGH(xA + 4096, Ab, ktb + i1, aOff1);
#pragma unroll
        for (int mi = 0; mi < 4; ++mi) {
            const int p = (wr * 64 + mi * 16 + l16) * 64 + quad * 16;
            af[mi] = *(const bf16x8*)(Abase + SWZ32(p));
        }
#pragma unroll
        for (int nj = 0; nj < 4; ++nj) {
            const int p = (wc * 64 + nj * 16 + l16) * 64 + quad * 16;
            bf[nj] = *(const bf16x8*)(Bbase + SWZ32(p));
        }
        BARF;
        CL_PRE;
#pragma unroll
        for (int mi = 0; mi < 4; ++mi)
#pragma unroll
            for (int nj = 0; nj < 4; ++nj)
                acc[mi][nj] = __builtin_amdgcn_mfma_f32_16x16x32_bf16(af[mi], bf[nj], acc[mi][nj], 0, 0, 0);
        CL_POST;
        BARF;

        // ---- P1: stage B(i+2)+A(i+2)-P0half -> current buf; read af-P1band ----
        STGH(oB,        Bb, ktb + i2, bOff0);
        STGH(oB + 4096, Bb, ktb + i2, bOff1);
        STGH(oA,        Ab, ktb + i2, aOff0);
#pragma unroll
        for (int mi = 0; mi < 4; ++mi) {
            const int p = (128 + wr * 64 + mi * 16 + l16) * 64 + quad * 16;
            af[mi] = *(const bf16x8*)(Abase + SWZ32(p));
        }
        BARF;
        CL_PRE;
#pragma unroll
        for (int mi = 0; mi < 4; ++mi)
#pragma unroll
            for (int nj = 0; nj < 4; ++nj)
                acc[4 + mi][nj] = __builtin_amdgcn_mfma_f32_16x16x32_bf16(af[mi], bf[nj], acc[4 + mi][nj], 0, 0, 0);
        CL_POST;
        asm volatile("s_waitcnt vmcnt(3)" ::: "memory");
        BARF;
    }

    if (SPLITK > 1 && blockIdx.y > 0) {
        float* po = part + (size_t)(blockIdx.y - 1) * ((size_t)M * N);
#pragma unroll
        for (int mi = 0; mi < 8; ++mi)
#pragma unroll
            for (int nj = 0; nj < 4; ++nj) {
                const int col = bn + wc * 64 + nj * 16 + l16;
#pragma unroll
                for (int r = 0; r < 4; ++r) {
                    const int row = bm + wr * 128 + mi * 16 + quad * 4 + r;
                    po[(size_t)row * N + col] = acc[mi][nj][r];
                }
            }
        return;
    }

#pragma unroll
    for (int mi = 0; mi < 8; ++mi) {
#pragma unroll
        for (int nj = 0; nj < 4; ++nj) {
            const int col = bn + wc * 64 + nj * 16 + l16;
            const float bv = bias[col];
#pragma unroll
            for (int r = 0; r < 4; ++r) {
                const int row = bm + wr * 128 + mi * 16 + quad * 4 + r;
                float v = acc[mi][nj][r] + bv;
                if (RESID == 1) v += ((const float*)resid)[(size_t)row * N + col];
                if (RESID == 2) v += bf2f(((const unsigned short*)resid)[(size_t)row * N + col]);
                if (GELU) {
                    const float u = v;
                    float c = 2.302204225929898f * (u + 0.044715f * u * u * u);
                    c = fminf(c, 80.f);
                    const float e = exp2f(c);
                    v = u * (e / (1.0f + e));
                }
                if (OUTBF16) ((unsigned short*)outp)[(size_t)row * N + col] = f2bf(v);
                else         ((float*)outp)[(size_t)row * N + col] = v;
            }
        }
    }
#undef STGH
#undef BARF
#undef CL_PRE
#undef CL_POST
}

// ---------------------------------------------------------------------------
// split-K merge: outp[i] += part[i], fp32, float4-vectorized
// ---------------------------------------------------------------------------
__global__ __launch_bounds__(256)
void splitk_add(const float* __restrict__ part, float* __restrict__ outp)
{
    const size_t i = ((size_t)blockIdx.x * 256 + threadIdx.x) * 4;
    float4 a = *(const float4*)(outp + i);
    const float4 p = *(const float4*)(part + i);
    a.x += p.x; a.y += p.y; a.z += p.z; a.w += p.w;
    *(float4*)(outp + i) = a;
}

// ---------------------------------------------------------------------------
// split qkv -> q (scaled by QSCALE), k [B*H, L, 64] bf16 + present-K fp32
// ---------------------------------------------------------------------------
__global__ __launch_bounds__(256)
void split_qkv(const unsigned short* __restrict__ qkv,
               unsigned short* __restrict__ q, unsigned short* __restrict__ k,
               float* __restrict__ present)
{
    const size_t idx = (size_t)blockIdx.x * 256 + threadIdx.x; // [2 sel][32 bh][2048 l][8 grp]
    const int g8  = idx & 7;
    const int l   = (idx >> 3) & 2047;
    const int bh  = (idx >> 14) & 31;
    const int sel = (int)(idx >> 19);
    const int b = bh >> 4, h = bh & 15;
    const unsigned short* src = qkv + (size_t)(l * BATCH + b) * (3 * DIM) + sel * DIM + h * HDIM + g8 * 8;
    const uint4 val = *(const uint4*)src;
    const unsigned short* sv = (const unsigned short*)&val;
    if (sel == 0) {
        unsigned short ov[8];
#pragma unroll
        for (int j = 0; j < 8; ++j) ov[j] = f2bf(bf2f(sv[j]) * QSCALE);
        *(uint4*)(q + ((size_t)bh * L_SEQ + l) * HDIM + g8 * 8) = *(uint4*)ov;
    } else {
        *(uint4*)(k + ((size_t)bh * L_SEQ + l) * HDIM + g8 * 8) = val;
        float* p = present + (((size_t)b * NH + h) * L_SEQ + l) * HDIM + (size_t)g8 * 8;
        float4 f0, f1;
        f0.x = bf2f(sv[0]); f0.y = bf2f(sv[1]); f0.z = bf2f(sv[2]); f0.w = bf2f(sv[3]);
        f1.x = bf2f(sv[4]); f1.y = bf2f(sv[5]); f1.z = bf2f(sv[6]); f1.w = bf2f(sv[7]);
        ((float4*)p)[0] = f0; ((float4*)p)[1] = f1;
    }
}

// ---------------------------------------------------------------------------
// V transpose: qkv v-columns -> vt [bh][64 d][2048 l] bf16, + present-V fp32
// ---------------------------------------------------------------------------
__global__ __launch_bounds__(256)
void transpose_v(const unsigned short* __restrict__ qkv, unsigned short* __restrict__ vt,
                 float* __restrict__ present)
{
    __shared__ unsigned short tile[64][72];
    const int lt = blockIdx.x;            // 0..31
    const int bh = blockIdx.y;            // 0..31
    const int b = bh >> 4, h = bh & 15;
    const int t = threadIdx.x;
#pragma unroll
    for (int i = 0; i < 2; ++i) {
        const int idx = i * 256 + t;
        const int l = idx >> 3, c = (idx & 7) * 8;
        const uint4 val =
            *(const uint4*)(qkv + (size_t)((lt * 64 + l) * BATCH + b) * (3 * DIM) + 2 * DIM + h * HDIM + c);
        *(uint4*)(&tile[l][c]) = val;
        const unsigned short* sv = (const unsigned short*)&val;
        float* p = present + ((((size_t)BATCH + b) * NH + h) * L_SEQ + lt * 64 + l) * HDIM + c;
        float4 f0, f1;
        f0.x = bf2f(sv[0]); f0.y = bf2f(sv[1]); f0.z = bf2f(sv[2]); f0.w = bf2f(sv[3]);
        f1.x = bf2f(sv[4]); f1.y = bf2f(sv[5]); f1.z = bf2f(sv[6]); f1.w = bf2f(sv[7]);
        ((float4*)p)[0] = f0; ((float4*)p)[1] = f1;
    }
    __syncthreads();
#pragma unroll
    for (int i = 0; i < 2; ++i) {
        const int idx = i * 256 + t;
        const int d = idx >> 3, l0 = (idx & 7) * 8;
        const int kk = l0 >> 3;
        ushort4 o[2];
        unsigned short* ov = (unsigned short*)o;
#pragma unroll
        for (int jj = 0; jj < 8; ++jj) {
            const int j = (jj + kk) & 7;
            ov[j] = tile[l0 + j][d];
        }
        *(uint4*)(vt + ((size_t)bh * HDIM + d) * L_SEQ + lt * 64 + l0) = *(uint4*)o;
    }
}

// ---------------------------------------------------------------------------
// Flash attention v2: S^T + static-max softmax, KEY-SPLIT 2-way,
// double-buffered K/V staged via global_load_lds (depth-2, counted vmcnt(4)).
// K/V tiles are [64][64] bf16 linear in LDS with 3-bit XOR swizzle
//   SWZA(p) = p ^ (((p>>7)&7)<<4)   (within each 128B row)
// staged with pre-swizzled global source + linear DMA dest (rule #21).
// Calendar per tile it (cb=it&1): read all K-frags -> bar -> stage K(it+2)
// into freed K region -> QK MFMA + softmax + PV -> bar -> stage V(it+2)
// into freed V region -> vmcnt(4) (drains tile it+1's 4 loads, leaves
// it+2's 4 in flight) -> bar. Branchless clamped tail (dead re-stages of
// tile 15 keep the vmcnt arithmetic exact).
// ---------------------------------------------------------------------------
#define SWZA(p) ((p) ^ ((((p) >> 7) & 7) << 4))

__global__ __launch_bounds__(256, 4)
void attn_kernel(const unsigned short* __restrict__ Q,
                 const unsigned short* __restrict__ Kk,
                 const unsigned short* __restrict__ Vt,
                 unsigned short* __restrict__ Opart,   // [2][4096][1024] bf16 unnormalized
                 float* __restrict__ Lpart)            // [2][32][2048] fp32
{
    const int qt = blockIdx.x;            // 0..15  (128 q rows each)
    const int ks = blockIdx.y;            // 0..1   (key split)
    const int bh = blockIdx.z;            // 0..31
    const int b = bh >> 4, h = bh & 15;
    const int t = threadIdx.x, w = t >> 6, lane = t & 63;
    const int quad = lane >> 4, l16 = lane & 15;

    __shared__ unsigned short Ksb[2][4096];    // [buf][64 key][64 d] swizzled
    __shared__ unsigned short Vsb[2][4096];    // [buf][64 d][64 key] swizzled
    __shared__ unsigned short Ps[4][32][72];   // per-wave P^T as [q][key]

    const size_t head_off = (size_t)bh * L_SEQ * HDIM;
    const int q_base = qt * 128 + w * 32;
    const int kt0 = ks * 1024;

    bf16x8 qf[2][2];
#pragma unroll
    for (int nf = 0; nf < 2; ++nf)
#pragma unroll
        for (int ds = 0; ds < 2; ++ds)
            qf[nf][ds] = *(const bf16x8*)(Q + head_off + (size_t)(q_base + nf*16 + l16) * HDIM + ds*32 + quad*8);

    // staging source offsets: thread covers LDS bytes pA=t*16 (round0) and
    // pB=4096+t*16 (round1) of the 8KB tile; source col pre-swizzled.
    const int pA = t * 16, pB = 4096 + t * 16;
    const int cA = (pA & 127) ^ (((pA >> 7) & 7) << 4);
    const int cB = (pB & 127) ^ (((pB >> 7) & 7) << 4);
    const int rA = pA >> 7, rB = pB >> 7;
    const size_t kOff0 = (size_t)rA * HDIM + (cA >> 1);
    const size_t kOff1 = (size_t)rB * HDIM + (cB >> 1);
    const size_t vOff0 = (size_t)rA * L_SEQ + (cA >> 1);
    const size_t vOff1 = (size_t)rB * L_SEQ + (cB >> 1);

#define STAGE_K(buf_, kt_) do {                                            \
        const unsigned short* g_ = Kk + head_off + (size_t)(kt_) * HDIM;   \
        load_lds16(g_ + kOff0, Ksb[buf_] + w * 512);                       \
        load_lds16(g_ + kOff1, Ksb[buf_] + 2048 + w * 512);                \
    } while (0)
#define STAGE_V(buf_, kt_) do {                                            \
        const unsigned short* g_ = Vt + head_off + (kt_);                  \
        load_lds16(g_ + vOff0, Vsb[buf_] + w * 512);                       \
        load_lds16(g_ + vOff1, Vsb[buf_] + 2048 + w * 512);                \
    } while (0)

    floatx4 o[4][2] = {};              // O^T[d=dt*16+quad*4+r][q=nf*16+l16]
    float l_i[2] = {0.f, 0.f};

    // prologue: stage tiles 0 and 1; wait tile0 (tile1's 4 loads in flight)
    STAGE_K(0, kt0);      STAGE_V(0, kt0);
    STAGE_K(1, kt0 + 64); STAGE_V(1, kt0 + 64);
    asm volatile("s_waitcnt vmcnt(4)" ::: "memory");
    __syncthreads();

    for (int it = 0; it < 16; ++it) {
        const int cb = it & 1;
        const int i2 = (it + 2 < 16) ? it + 2 : 15;
        const unsigned short* Kl = Ksb[cb];
        const unsigned short* Vl = Vsb[cb];

        // K fragments to registers (swizzled read, b128 bank floor)
        bf16x8 kf[2][4];
#pragma unroll
        for (int ds = 0; ds < 2; ++ds)
#pragma unroll
            for (int jt = 0; jt < 4; ++jt) {
                const int p = (jt*16 + l16) * 128 + ds*64 + quad*16;
                kf[ds][jt] = *(const bf16x8*)((const char*)Kl + SWZA(p));
            }
        __syncthreads();                       // all waves done reading Ksb[cb]
        STAGE_K(cb, kt0 + i2 * 64);            // K(it+2) -> freed region

        // S^T[key][q] = K @ Q^T
        floatx4 s[4][2] = {};
#pragma unroll
        for (int ds = 0; ds < 2; ++ds)
#pragma unroll
            for (int jt = 0; jt < 4; ++jt) {
                s[jt][0] = __builtin_amdgcn_mfma_f32_16x16x32_bf16(kf[ds][jt], qf[0][ds], s[jt][0], 0, 0, 0);
                s[jt][1] = __builtin_amdgcn_mfma_f32_16x16x32_bf16(kf[ds][jt], qf[1][ds], s[jt][1], 0, 0, 0);
            }

        // p = exp2(s); per-lane l accumulation; pack to bf16 via v_perm
#pragma unroll
        for (int nf = 0; nf < 2; ++nf)
#pragma unroll
            for (int jt = 0; jt < 4; ++jt) {
                const float p0 = exp2f(s[jt][nf][0]);
                const float p1 = exp2f(s[jt][nf][1]);
                const float p2 = exp2f(s[jt][nf][2]);
                const float p3 = exp2f(s[jt][nf][3]);
                l_i[nf] += (p0 + p1) + (p2 + p3);
                uint2 pk;
                pk.x = __builtin_amdgcn_perm(fbits(p1), fbits(p0), 0x07060302u);
                pk.y = __builtin_amdgcn_perm(fbits(p3), fbits(p2), 0x07060302u);
                *(uint2*)(&Ps[w][nf*16 + l16][jt*16 + quad*4]) = pk;
            }

        // O^T += V^T @ P^T
#pragma unroll
        for (int kk = 0; kk < 2; ++kk) {
            const bf16x8 pf0 = *(const bf16x8*)(&Ps[w][l16]     [kk*32 + quad*8]);
            const bf16x8 pf1 = *(const bf16x8*)(&Ps[w][16 + l16][kk*32 + quad*8]);
#pragma unroll
            for (int dt = 0; dt < 4; ++dt) {
                const int p = (dt*16 + l16) * 128 + kk*64 + quad*16;
                const bf16x8 vf = *(const bf16x8*)((const char*)Vl + SWZA(p));
                o[dt][0] = __builtin_amdgcn_mfma_f32_16x16x32_bf16(vf, pf0, o[dt][0], 0, 0, 0);
                o[dt][1] = __builtin_amdgcn_mfma_f32_16x16x32_bf16(vf, pf1, o[dt][1], 0, 0, 0);
            }
        }
        __syncthreads();                       // all waves done reading Vsb[cb]
        STAGE_V(cb, kt0 + i2 * 64);            // V(it+2) -> freed region
        // drain tile it+1's 4 loads; leave tile it+2's 4 in flight
        asm volatile("s_waitcnt vmcnt(4)" ::: "memory");
        __syncthreads();
    }

    unsigned short* Op = Opart + (size_t)ks * ROWS * DIM;
#pragma unroll
    for (int nf = 0; nf < 2; ++nf) {
        float l = l_i[nf];
        l += __shfl_xor(l, 16, 64);
        l += __shfl_xor(l, 32, 64);
        const int q = q_base + nf*16 + l16;
        if (quad == 0)
            Lpart[((size_t)ks * 32 + bh) * L_SEQ + q] = l;
#pragma unroll
        for (int dt = 0; dt < 4; ++dt) {
            ushort4 ov;
            ov.x = f2bf(o[dt][nf][0]); ov.y = f2bf(o[dt][nf][1]);
            ov.z = f2bf(o[dt][nf][2]); ov.w = f2bf(o[dt][nf][3]);
            *(ushort4*)(Op + (size_t)(q * BATCH + b) * DIM + h * HDIM + dt*16 + quad*4) = ov;
        }
    }
#undef STAGE_K
#undef STAGE_V
}

// ---------------------------------------------------------------------------
// Merge: aw[row][col] = (O0+O1) / (l0+l1), bf16. One block per row.
// ---------------------------------------------------------------------------
__global__ __launch_bounds__(256)
void attn_merge(const unsigned short* __restrict__ Opart,
                const float* __restrict__ Lpart,
                unsigned short* __restrict__ Aout)
{
    const int row = blockIdx.x;           // 0..4095 (= q*BATCH + b)
    const int q = row >> 1, b = row & 1;
    const int t = threadIdx.x;
    const int col = t * 4;
    const int h = col >> 6;
    const int bh = b * 16 + h;
    const float l0 = Lpart[(size_t)bh * L_SEQ + q];
    const float l1 = Lpart[((size_t)32 + bh) * L_SEQ + q];
    const float inv = 1.0f / (l0 + l1);
    const ushort4 o0 = *(const ushort4*)(Opart + (size_t)row * DIM + col);
    const ushort4 o1 = *(const ushort4*)(Opart + (size_t)ROWS * DIM + (size_t)row * DIM + col);
    ushort4 ov;
    ov.x = f2bf((bf2f(o0.x) + bf2f(o1.x)) * inv);
    ov.y = f2bf((bf2f(o0.y) + bf2f(o1.y)) * inv);
    ov.z = f2bf((bf2f(o0.z) + bf2f(o1.z)) * inv);
    ov.w = f2bf((bf2f(o0.w) + bf2f(o1.w)) * inv);
    *(ushort4*)(Aout + (size_t)row * DIM + col) = ov;
}

// ---------------------------------------------------------------------------
// Launch
// ---------------------------------------------------------------------------
extern "C" void kernel_launch(void* const* d_in, const int* in_sizes, int n_in,
                              void* d_out, int out_size, void* d_ws, size_t ws_size,
                              hipStream_t stream)
{
    const float* x      = (const float*)d_in[0];
    const float* ln1_g  = (const float*)d_in[1];
    const float* ln1_b  = (const float*)d_in[2];
    const float* w_attn = (const float*)d_in[3];
    const float* b_attn = (const float*)d_in[4];
    const float* w_proj = (const float*)d_in[5];
    const float* b_proj = (const float*)d_in[6];
    const float* ln2_g  = (const float*)d_in[7];
    const float* ln2_b  = (const float*)d_in[8];
    const float* w_fc   = (const float*)d_in[9];
    const float* b_fc   = (const float*)d_in[10];
    const float* w_out  = (const float*)d_in[11];
    const float* b_out  = (const float*)d_in[12];

    char* ws = (char*)d_ws;
    unsigned short* watT   = (unsigned short*)(ws + 0);           // [3072,1024] bf16
    unsigned short* wprojT = (unsigned short*)(ws + 6291456);     // [1024,1024]
    unsigned short* wfcT   = (unsigned short*)(ws + 8388608);     // [4096,1024]
    unsigned short* woutT  = (unsigned short*)(ws + 16777216);    // [1024,4096]
    unsigned short* h      = (unsigned short*)(ws + 25165824);    // [4096,1024]
    unsigned short* qkv    = (unsigned short*)(ws + 33554432);    // [4096,3072]
    // After split/transpose_v, qkv region is dead -> reuse for attn partials:
    unsigned short* opart  = (unsigned short*)(ws + 33554432);    // [2][4096][1024] bf16 (16MB)
    float*          lpart  = (float*)(ws + 50331648);             // [2][32][2048] fp32 (512KB)
    unsigned short* mws    = (unsigned short*)(ws + 33554432);    // [4096,4096] (reuses region later)
    unsigned short* qw     = (unsigned short*)(ws + 58720256);    // [32,2048,64]
    unsigned short* kw     = (unsigned short*)(ws + 67108864);    // [32,2048,64]
    unsigned short* vt     = (unsigned short*)(ws + 75497472);    // [32,64,2048] (transposed V)
    unsigned short* aw     = (unsigned short*)(ws + 83886080);    // [4096,1024]
    unsigned short* x2     = (unsigned short*)(ws + 92274688);    // [4096,1024] bf16 residual stream
    // split-K partial for the out GEMM: 16MB fp32, reuses vt+aw (dead at step 9)
    float*          kpart  = (float*)(ws + 75497472);             // [4096,1024] fp32

    float* xout    = (float*)d_out;                // [2048,2,1024]
    float* present = (float*)d_out + 4194304;      // [2,2,16,2048,64]

    // 1. all weight transposes (fp32 -> bf16 [N,K])
    transpose_all<<<12288, 256, 0, stream>>>(w_attn, watT, w_proj, wprojT, w_fc, wfcT, w_out, woutT);

    // 2. LN1
    ln_rows<0><<<ROWS, 256, 0, stream>>>(x, ln1_g, ln1_b, h);
    // 3. QKV GEMM -> bf16 (256^2 deep-pipelined v2, 16x12 = 192 blocks)
    gemm256b<0,0,1,1><<<dim3(192), 512, 0, stream>>>(h, watT, b_attn, nullptr, qkv, nullptr, ROWS, 3*DIM, DIM, 16);
    // 4. split (q scaled, k, present-K) + V transpose (+present-V)
    split_qkv<<<4096, 256, 0, stream>>>(qkv, qw, kw, present);
    transpose_v<<<dim3(32, 32), 256, 0, stream>>>(qkv, vt, present);
    // 5. attention (key-split x2 -> 1024 blocks) + merge
    attn_kernel<<<dim3(16, 2, 32), 256, 0, stream>>>(qw, kw, vt, opart, lpart);
    attn_merge<<<ROWS, 256, 0, stream>>>(opart, lpart, aw);
    // 6. proj + residual -> x2 bf16 (64x128 tiles: 512 blocks)
    gemm_bt<0,1,1,2,1><<<dim3(64, 8), 256, 0, stream>>>(aw, wprojT, b_proj, x, x2, nullptr, ROWS, DIM, DIM);
    // 7. LN2 (bf16 input)
    ln_rows<1><<<ROWS, 256, 0, stream>>>(x2, ln2_g, ln2_b, h);
    // 8. FC + GELU -> bf16 (256^2 deep-pipelined v2, 16x16 = 256 blocks)
    gemm256b<1,0,1,1><<<dim3(256), 512, 0, stream>>>(h, wfcT, b_fc, nullptr, mws, nullptr, ROWS, DFF_, DIM, 16);
    // 9. out GEMM, 128x128 tile + split-K 2 (grid 32x8x2 = 512 blocks, 2/CU)
    gemm_bt<0,2,0,4,2><<<dim3(32, 8, 2), 256, 0, stream>>>(mws, woutT, b_out, x2, xout, kpart, ROWS, DIM, DFF_);
    splitk_add<<<4096, 256, 0, stream>>>(kpart, xout);
}

// Round 7
// 403.720 us; speedup vs baseline: 1.0240x; 1.0240x over previous
//
#include <hip/hip_runtime.h>
#include <stdint.h>

// Problem constants
#define L_SEQ 2048
#define BATCH 2
#define DIM   1024
#define NH    16
#define HDIM  64
#define DFF_  4096
#define ROWS  (L_SEQ*BATCH)   // 4096 token rows, row index = l*BATCH + b

// softmax scale folded into Q at split time: (1/sqrt(64)) * log2(e)
#define QSCALE 0.18033688011112042f

typedef __attribute__((ext_vector_type(8))) short  bf16x8;
typedef __attribute__((ext_vector_type(4))) float  floatx4;

__device__ __forceinline__ unsigned short f2bf(float f) {
    union { float f; uint32_t u; } x; x.f = f;
    uint32_t r = x.u + 0x7fffu + ((x.u >> 16) & 1u);   // RNE
    return (unsigned short)(r >> 16);
}
__device__ __forceinline__ float bf2f(unsigned short b) {
    union { uint32_t u; float f; } x; x.u = ((uint32_t)b) << 16;
    return x.f;
}
__device__ __forceinline__ uint32_t fbits(float f) {
    union { float f; uint32_t u; } x; x.f = f; return x.u;
}

// async global->LDS, 16B per lane; lds dest = wave-uniform base + lane*16
__device__ __forceinline__ void load_lds16(const unsigned short* g, unsigned short* l) {
    __builtin_amdgcn_global_load_lds(
        (const __attribute__((address_space(1))) unsigned int*)g,
        (__attribute__((address_space(3))) unsigned int*)l, 16, 0, 0);
}

// ---------------------------------------------------------------------------
// All 4 weight transposes in one kernel: fp32 [K,N] -> bf16 [N,K], 32x32 tiles
// ---------------------------------------------------------------------------
__global__ __launch_bounds__(256)
void transpose_all(const float* __restrict__ s0, unsigned short* __restrict__ d0,
                   const float* __restrict__ s1, unsigned short* __restrict__ d1,
                   const float* __restrict__ s2, unsigned short* __restrict__ d2,
                   const float* __restrict__ s3, unsigned short* __restrict__ d3)
{
    const int id = blockIdx.x;
    const float* src; unsigned short* dst; int K, N, local;
    if (id < 3072)      { src = s0; dst = d0; K = 1024; N = 3072; local = id; }
    else if (id < 4096) { src = s1; dst = d1; K = 1024; N = 1024; local = id - 3072; }
    else if (id < 8192) { src = s2; dst = d2; K = 1024; N = 4096; local = id - 4096; }
    else                { src = s3; dst = d3; K = 4096; N = 1024; local = id - 8192; }
    const int nN = N >> 5;
    const int bk = (local / nN) * 32, bn = (local % nN) * 32;

    __shared__ float tile[32][36];
    const int t = threadIdx.x;
    const int r = t >> 3, c4 = (t & 7) * 4;
    *(float4*)&tile[r][c4] = *(const float4*)(src + (size_t)(bk + r) * N + bn + c4);
    __syncthreads();
    ushort4 o;
    o.x = f2bf(tile[c4 + 0][r]);
    o.y = f2bf(tile[c4 + 1][r]);
    o.z = f2bf(tile[c4 + 2][r]);
    o.w = f2bf(tile[c4 + 3][r]);
    *(ushort4*)(dst + (size_t)(bn + r) * K + bk + c4) = o;
}

// ---------------------------------------------------------------------------
// LayerNorm: [4096,1024] fp32 or bf16 input -> bf16 out, one block per row
// ---------------------------------------------------------------------------
template<int INBF16>
__global__ __launch_bounds__(256)
void ln_rows(const void* __restrict__ xin, const float* __restrict__ g,
             const float* __restrict__ bta, unsigned short* __restrict__ out)
{
    const int row = blockIdx.x;
    const int t = threadIdx.x;
    float4 v;
    if (INBF16) {
        const ushort4 u = ((const ushort4*)((const unsigned short*)xin + (size_t)row * DIM))[t];
        v.x = bf2f(u.x); v.y = bf2f(u.y); v.z = bf2f(u.z); v.w = bf2f(u.w);
    } else {
        v = ((const float4*)((const float*)xin + (size_t)row * DIM))[t];
    }
    float s  = v.x + v.y + v.z + v.w;
    float s2 = v.x*v.x + v.y*v.y + v.z*v.z + v.w*v.w;
#pragma unroll
    for (int d = 1; d < 64; d <<= 1) { s += __shfl_xor(s, d, 64); s2 += __shfl_xor(s2, d, 64); }
    __shared__ float ss[4], ss2[4];
    const int w = t >> 6, lane = t & 63;
    if (lane == 0) { ss[w] = s; ss2[w] = s2; }
    __syncthreads();
    s  = ss[0] + ss[1] + ss[2] + ss[3];
    s2 = ss2[0] + ss2[1] + ss2[2] + ss2[3];
    const float mu   = s * (1.0f / DIM);
    const float var  = s2 * (1.0f / DIM) - mu * mu;
    const float rstd = rsqrtf(var + 1e-5f);
    const float4 gv = ((const float4*)g)[t];
    const float4 bv = ((const float4*)bta)[t];
    ushort4 o;
    o.x = f2bf((v.x - mu) * rstd * gv.x + bv.x);
    o.y = f2bf((v.y - mu) * rstd * gv.y + bv.y);
    o.z = f2bf((v.z - mu) * rstd * gv.z + bv.z);
    o.w = f2bf((v.w - mu) * rstd * gv.w + bv.w);
    *(ushort4*)(out + (size_t)row * DIM + t * 4) = o;
}

// ---------------------------------------------------------------------------
// bf16 GEMM, B^T input (Bt [N,K]); C = A@B + bias (+resid) (gelu?)
// MI=4: 128x128 tile; MI=2: 64x128 tile. BK=32, m97 structure.
// RESID: 0=none, 1=fp32, 2=bf16
// SPLITK>1: blockIdx.z = K-slice; kz>0 writes raw fp32 partial.
// ---------------------------------------------------------------------------
template<int GELU, int RESID, int OUTBF16, int MI, int SPLITK>
__global__ __launch_bounds__(256)
void gemm_bt(const unsigned short* __restrict__ A,   // [M,K] bf16
             const unsigned short* __restrict__ Bt,  // [N,K] bf16
             const float* __restrict__ bias,         // [N]
             const void* __restrict__ resid,         // [M,N] fp32/bf16 or null
             void* __restrict__ outp,                // bf16 or fp32 [M,N]
             float* __restrict__ part,               // fp32 partials (SPLITK>1)
             int M, int N, int K)
{
    __shared__ unsigned short As[MI * 32 * 32];   // flat, unpadded
    __shared__ unsigned short Bs[128 * 32];
    const int t = threadIdx.x;
    const int w = t >> 6, lane = t & 63;
    const int quad = lane >> 4, l16 = lane & 15;
    const int wm = (w >> 1) * (MI * 16), wn = (w & 1) * 64;
    const int bm = blockIdx.x * (MI * 32), bn = blockIdx.y * 128;

    const int srow = lane >> 2;
    const int scol = (lane & 3) * 8;

    const unsigned short* Ab = A  + (size_t)bm * K;
    const unsigned short* Bb = Bt + (size_t)bn * K;

    floatx4 acc[MI][4] = {};

    const int kspan = (SPLITK > 1) ? (K / SPLITK) : K;
    const int k0    = (SPLITK > 1) ? blockIdx.z * kspan : 0;

    for (int kc = k0; kc < k0 + kspan; kc += 32) {
        __syncthreads();
#pragma unroll
        for (int i = 0; i < MI / 2; ++i) {
            const int r0 = (i * 4 + w) * 16;
            load_lds16(Ab + (size_t)(r0 + srow) * K + kc + scol, As + r0 * 32);
        }
#pragma unroll
        for (int i = 0; i < 2; ++i) {
            const int r0 = (i * 4 + w) * 16;
            load_lds16(Bb + (size_t)(r0 + srow) * K + kc + scol, Bs + r0 * 32);
        }
        __syncthreads();
        bf16x8 af[MI], bf[4];
#pragma unroll
        for (int i = 0; i < MI; ++i) af[i] = *(const bf16x8*)(As + (wm + i*16 + l16) * 32 + quad * 8);
#pragma unroll
        for (int j = 0; j < 4; ++j) bf[j] = *(const bf16x8*)(Bs + (wn + j*16 + l16) * 32 + quad * 8);
#pragma unroll
        for (int i = 0; i < MI; ++i)
#pragma unroll
            for (int j = 0; j < 4; ++j)
                acc[i][j] = __builtin_amdgcn_mfma_f32_16x16x32_bf16(af[i], bf[j], acc[i][j], 0, 0, 0);
    }

    if (SPLITK > 1 && blockIdx.z > 0) {
        float* po = part + (size_t)(blockIdx.z - 1) * ((size_t)M * N);
#pragma unroll
        for (int i = 0; i < MI; ++i)
#pragma unroll
            for (int j = 0; j < 4; ++j) {
                const int col = bn + wn + j*16 + l16;
#pragma unroll
                for (int r = 0; r < 4; ++r) {
                    const int row = bm + wm + i*16 + quad*4 + r;
                    po[(size_t)row * N + col] = acc[i][j][r];
                }
            }
        return;
    }

#pragma unroll
    for (int i = 0; i < MI; ++i) {
#pragma unroll
        for (int j = 0; j < 4; ++j) {
            const int col = bn + wn + j*16 + l16;
            const float bv = bias[col];
#pragma unroll
            for (int r = 0; r < 4; ++r) {
                const int row = bm + wm + i*16 + quad*4 + r;
                float v = acc[i][j][r] + bv;
                if (RESID == 1) v += ((const float*)resid)[(size_t)row * N + col];
                if (RESID == 2) v += bf2f(((const unsigned short*)resid)[(size_t)row * N + col]);
                if (GELU) {
                    const float u = v;
                    float c = 2.302204225929898f * (u + 0.044715f * u * u * u);
                    c = fminf(c, 80.f);
                    const float e = exp2f(c);
                    v = u * (e / (1.0f + e));
                }
                if (OUTBF16) ((unsigned short*)outp)[(size_t)row * N + col] = f2bf(v);
                else         ((float*)outp)[(size_t)row * N + col] = v;
            }
        }
    }
}

// ---------------------------------------------------------------------------
// 256x256-tile deep-pipelined GEMM v2, BK=32, 64 KiB STATIC LDS.
// (schedule unchanged from R4 — verified: bank-conflict 0, out of top-5)
// ---------------------------------------------------------------------------
#define SWZ32(p) ((p) ^ ((((p) >> 7) & 3) << 4))

template<int GELU, int OUTBF16>
__global__ __launch_bounds__(512, 2)
void gemm256b(const unsigned short* __restrict__ A,   // [M,K] bf16
              const unsigned short* __restrict__ Bt,  // [N,K] bf16
              const float* __restrict__ bias,         // [N]
              void* __restrict__ outp,                // bf16 or fp32 [M,N]
              int M, int N, int K, int nbx)
{
    __shared__ unsigned short lds[32768];            // 64 KiB exactly
    const int t = threadIdx.x;
    const int w = t >> 6, lane = t & 63;
    const int quad = lane >> 4, l16 = lane & 15;
    const int wr = w >> 2, wc = w & 3;

    // bijective XCD swizzle (gridDim.x % 8 == 0)
    const int nwg = gridDim.x;
    const int cpx = nwg >> 3;
    const int bid = (blockIdx.x & 7) * cpx + (blockIdx.x >> 3);
    const int bm = (bid % nbx) * 256, bn = (bid / nbx) * 256;

    const unsigned short* Ab = A  + (size_t)bm * K;
    const unsigned short* Bb = Bt + (size_t)bn * K;

    // staging source offsets for an 8KB half staged at half-local byte t*16
    const int sh   = SWZ32(t * 16);          // [0,8192)
    const int rp0  = sh >> 6;                // swizzled row within half [0,128)
    const int colE = (sh & 63) >> 1;         // element col within BK=32
    const int w0 = rp0 & 63, hb = rp0 >> 6;  // band-within / band-half bit
    // B: linear rows per half
    const size_t bOff0 = (size_t)rp0 * K + colE;
    const size_t bOff1 = (size_t)(128 + rp0) * K + colE;
    // A: band-permuted rows
    const size_t aOff0 = (size_t)(w0 + hb * 128)      * K + colE;  // bands 0,1
    const size_t aOff1 = (size_t)(w0 + hb * 128 + 64) * K + colE;  // bands 2,3

#define STGH(dstE_, srcp_, kta_, off_) \
    load_lds16((srcp_) + (size_t)(kta_) * 32 + (off_), lds + (dstE_) + w * 512)
#define BARF    do { __builtin_amdgcn_s_barrier(); asm volatile("" ::: "memory"); } while (0)
#define CL_PRE  do { asm volatile("s_waitcnt lgkmcnt(0)" ::: "memory");    \
                     __builtin_amdgcn_sched_barrier(0);                    \
                     __builtin_amdgcn_s_setprio(1); } while (0)
#define CL_POST do { __builtin_amdgcn_s_setprio(0);                        \
                     __builtin_amdgcn_sched_barrier(0); } while (0)

    floatx4 acc[8][4] = {};
    const int nt = K >> 5;

    // prologue: tiles 0,1 fully staged; wait tile0
    STGH(0,     Ab, 0, aOff0);  STGH(4096,  Ab, 0, aOff1);
    STGH(8192,  Bb, 0, bOff0);  STGH(12288, Bb, 0, bOff1);
    STGH(16384, Ab, 1, aOff0);  STGH(20480, Ab, 1, aOff1);
    STGH(24576, Bb, 1, bOff0);  STGH(28672, Bb, 1, bOff1);
    asm volatile("s_waitcnt vmcnt(4)" ::: "memory");
    BARF;

    for (int i = 0; i < nt; ++i) {
        const int cb = i & 1;
        const int i1 = (i + 1 < nt) ? i + 1 : nt - 1;
        const int i2 = (i + 2 < nt) ? i + 2 : nt - 1;
        const int oA = cb * 16384, oB = oA + 8192;
        const int xA = (cb ^ 1) * 16384;
        const char* Abase = (const char*)lds + cb * 32768;
        const char* Bbase = Abase + 16384;
        bf16x8 af[4], bf[4];

        // ---- P0: stage A(i+1)-P1half -> other buf; read af-P0band + bf-all ----
        STGH(xA + 4096, Ab, i1, aOff1);
#pragma unroll
        for (int mi = 0; mi < 4; ++mi) {
            const int p = (wr * 64 + mi * 16 + l16) * 64 + quad * 16;
            af[mi] = *(const bf16x8*)(Abase + SWZ32(p));
        }
#pragma unroll
        for (int nj = 0; nj < 4; ++nj) {
            const int p = (wc * 64 + nj * 16 + l16) * 64 + quad * 16;
            bf[nj] = *(const bf16x8*)(Bbase + SWZ32(p));
        }
        BARF;
        CL_PRE;
#pragma unroll
        for (int mi = 0; mi < 4; ++mi)
#pragma unroll
            for (int nj = 0; nj < 4; ++nj)
                acc[mi][nj] = __builtin_amdgcn_mfma_f32_16x16x32_bf16(af[mi], bf[nj], acc[mi][nj], 0, 0, 0);
        CL_POST;
        BARF;

        // ---- P1: stage B(i+2)+A(i+2)-P0half -> current buf; read af-P1band ----
        STGH(oB,        Bb, i2, bOff0);
        STGH(oB + 4096, Bb, i2, bOff1);
        STGH(oA,        Ab, i2, aOff0);
#pragma unroll
        for (int mi = 0; mi < 4; ++mi) {
            const int p = (128 + wr * 64 + mi * 16 + l16) * 64 + quad * 16;
            af[mi] = *(const bf16x8*)(Abase + SWZ32(p));
        }
        BARF;
        CL_PRE;
#pragma unroll
        for (int mi = 0; mi < 4; ++mi)
#pragma unroll
            for (int nj = 0; nj < 4; ++nj)
                acc[4 + mi][nj] = __builtin_amdgcn_mfma_f32_16x16x32_bf16(af[mi], bf[nj], acc[4 + mi][nj], 0, 0, 0);
        CL_POST;
        asm volatile("s_waitcnt vmcnt(3)" ::: "memory");
        BARF;
    }

#pragma unroll
    for (int mi = 0; mi < 8; ++mi) {
#pragma unroll
        for (int nj = 0; nj < 4; ++nj) {
            const int col = bn + wc * 64 + nj * 16 + l16;
            const float bv = bias[col];
#pragma unroll
            for (int r = 0; r < 4; ++r) {
                const int row = bm + wr * 128 + mi * 16 + quad * 4 + r;
                float v = acc[mi][nj][r] + bv;
                if (GELU) {
                    const float u = v;
                    float c = 2.302204225929898f * (u + 0.044715f * u * u * u);
                    c = fminf(c, 80.f);
                    const float e = exp2f(c);
                    v = u * (e / (1.0f + e));
                }
                if (OUTBF16) ((unsigned short*)outp)[(size_t)row * N + col] = f2bf(v);
                else         ((float*)outp)[(size_t)row * N + col] = v;
            }
        }
    }
#undef STGH
#undef BARF
#undef CL_PRE
#undef CL_POST
}

// ---------------------------------------------------------------------------
// split-K merge: outp[i] += part[i], fp32, float4-vectorized
// ---------------------------------------------------------------------------
__global__ __launch_bounds__(256)
void splitk_add(const float* __restrict__ part, float* __restrict__ outp)
{
    const size_t i = ((size_t)blockIdx.x * 256 + threadIdx.x) * 4;
    float4 a = *(const float4*)(outp + i);
    const float4 p = *(const float4*)(part + i);
    a.x += p.x; a.y += p.y; a.z += p.z; a.w += p.w;
    *(float4*)(outp + i) = a;
}

// ---------------------------------------------------------------------------
// split qkv -> q (scaled by QSCALE), k [B*H, L, 64] bf16 + present-K fp32
// ---------------------------------------------------------------------------
__global__ __launch_bounds__(256)
void split_qkv(const unsigned short* __restrict__ qkv,
               unsigned short* __restrict__ q, unsigned short* __restrict__ k,
               float* __restrict__ present)
{
    const size_t idx = (size_t)blockIdx.x * 256 + threadIdx.x; // [2 sel][32 bh][2048 l][8 grp]
    const int g8  = idx & 7;
    const int l   = (idx >> 3) & 2047;
    const int bh  = (idx >> 14) & 31;
    const int sel = (int)(idx >> 19);
    const int b = bh >> 4, h = bh & 15;
    const unsigned short* src = qkv + (size_t)(l * BATCH + b) * (3 * DIM) + sel * DIM + h * HDIM + g8 * 8;
    const uint4 val = *(const uint4*)src;
    const unsigned short* sv = (const unsigned short*)&val;
    if (sel == 0) {
        unsigned short ov[8];
#pragma unroll
        for (int j = 0; j < 8; ++j) ov[j] = f2bf(bf2f(sv[j]) * QSCALE);
        *(uint4*)(q + ((size_t)bh * L_SEQ + l) * HDIM + g8 * 8) = *(uint4*)ov;
    } else {
        *(uint4*)(k + ((size_t)bh * L_SEQ + l) * HDIM + g8 * 8) = val;
        float* p = present + (((size_t)b * NH + h) * L_SEQ + l) * HDIM + (size_t)g8 * 8;
        float4 f0, f1;
        f0.x = bf2f(sv[0]); f0.y = bf2f(sv[1]); f0.z = bf2f(sv[2]); f0.w = bf2f(sv[3]);
        f1.x = bf2f(sv[4]); f1.y = bf2f(sv[5]); f1.z = bf2f(sv[6]); f1.w = bf2f(sv[7]);
        ((float4*)p)[0] = f0; ((float4*)p)[1] = f1;
    }
}

// ---------------------------------------------------------------------------
// V transpose: qkv v-columns -> vt [bh][64 d][2048 l] bf16, + present-V fp32
// ---------------------------------------------------------------------------
__global__ __launch_bounds__(256)
void transpose_v(const unsigned short* __restrict__ qkv, unsigned short* __restrict__ vt,
                 float* __restrict__ present)
{
    __shared__ unsigned short tile[64][72];
    const int lt = blockIdx.x;            // 0..31
    const int bh = blockIdx.y;            // 0..31
    const int b = bh >> 4, h = bh & 15;
    const int t = threadIdx.x;
#pragma unroll
    for (int i = 0; i < 2; ++i) {
        const int idx = i * 256 + t;
        const int l = idx >> 3, c = (idx & 7) * 8;
        const uint4 val =
            *(const uint4*)(qkv + (size_t)((lt * 64 + l) * BATCH + b) * (3 * DIM) + 2 * DIM + h * HDIM + c);
        *(uint4*)(&tile[l][c]) = val;
        const unsigned short* sv = (const unsigned short*)&val;
        float* p = present + ((((size_t)BATCH + b) * NH + h) * L_SEQ + lt * 64 + l) * HDIM + c;
        float4 f0, f1;
        f0.x = bf2f(sv[0]); f0.y = bf2f(sv[1]); f0.z = bf2f(sv[2]); f0.w = bf2f(sv[3]);
        f1.x = bf2f(sv[4]); f1.y = bf2f(sv[5]); f1.z = bf2f(sv[6]); f1.w = bf2f(sv[7]);
        ((float4*)p)[0] = f0; ((float4*)p)[1] = f1;
    }
    __syncthreads();
#pragma unroll
    for (int i = 0; i < 2; ++i) {
        const int idx = i * 256 + t;
        const int d = idx >> 3, l0 = (idx & 7) * 8;
        const int kk = l0 >> 3;
        ushort4 o[2];
        unsigned short* ov = (unsigned short*)o;
#pragma unroll
        for (int jj = 0; jj < 8; ++jj) {
            const int j = (jj + kk) & 7;
            ov[j] = tile[l0 + j][d];
        }
        *(uint4*)(vt + ((size_t)bh * HDIM + d) * L_SEQ + lt * 64 + l0) = *(uint4*)o;
    }
}

// ---------------------------------------------------------------------------
// Flash attention v3: S^T + static-max softmax, KEY-SPLIT 2-way.
// Register-staged K/V (R4 structure) with:
//  - T14 hoist: global loads for tile it+1 issue at the TOP of tile it,
//    ds_writes after the post-compute barrier (vmcnt auto-inserted).
//  - Compact XOR-swizzled LDS (32 KB): Ks[64][64], Vts[64][64], Ps[4][32][64].
//    Same involution on write and read: byte ^= ((row&7)<<4) within 128B row.
//  - 2 barriers per tile.
// ---------------------------------------------------------------------------
#define SWZA(p) ((p) ^ ((((p) >> 7) & 7) << 4))

__global__ __launch_bounds__(256, 4)
void attn_kernel(const unsigned short* __restrict__ Q,
                 const unsigned short* __restrict__ Kk,
                 const unsigned short* __restrict__ Vt,
                 unsigned short* __restrict__ Opart,   // [2][4096][1024] bf16 unnormalized
                 float* __restrict__ Lpart)            // [2][32][2048] fp32
{
    const int qt = blockIdx.x;            // 0..15  (128 q rows each)
    const int ks = blockIdx.y;            // 0..1   (key split)
    const int bh = blockIdx.z;            // 0..31
    const int b = bh >> 4, h = bh & 15;
    const int t = threadIdx.x, w = t >> 6, lane = t & 63;
    const int quad = lane >> 4, l16 = lane & 15;

    __shared__ unsigned short Ks[4096];       // [64 key][64 d] swizzled, 8KB
    __shared__ unsigned short Vts[4096];      // [64 d][64 key] swizzled, 8KB
    __shared__ unsigned short Ps[4][2048];    // per-wave [32 q][64 key] swz, 16KB

    const size_t head_off = (size_t)bh * L_SEQ * HDIM;
    const int q_base = qt * 128 + w * 32;
    const int kt0 = ks * 1024;

    bf16x8 qf[2][2];
#pragma unroll
    for (int nf = 0; nf < 2; ++nf)
#pragma unroll
        for (int ds = 0; ds < 2; ++ds)
            qf[nf][ds] = *(const bf16x8*)(Q + head_off + (size_t)(q_base + nf*16 + l16) * HDIM + ds*32 + quad*8);

    // staging map: thread covers rows sr, sr+32; 16B chunk c8 = t&7
    const int sr = t >> 3;
    const int c8 = t & 7;
    const int sc = c8 * 8;                                    // element col
    const int wb = sr * 128 + ((c8 * 16) ^ ((sr & 7) << 4));  // swz byte off (row sr)
    // (sr+32)&7 == sr&7 -> same column XOR for the second row
    const int wb2 = wb + 32 * 128;

    uint4 kreg0, kreg1, vreg0, vreg1;

#define LOAD_TILE(kt_) do {                                                              \
        kreg0 = *(const uint4*)(Kk + head_off + (size_t)((kt_) + sr) * HDIM + sc);       \
        kreg1 = *(const uint4*)(Kk + head_off + (size_t)((kt_) + sr + 32) * HDIM + sc);  \
        vreg0 = *(const uint4*)(Vt + head_off + (size_t)sr * L_SEQ + (kt_) + sc);        \
        vreg1 = *(const uint4*)(Vt + head_off + (size_t)(sr + 32) * L_SEQ + (kt_) + sc); \
    } while (0)
#define WRITE_TILE() do {                                                                \
        *(uint4*)((char*)Ks + wb)   = kreg0;                                             \
        *(uint4*)((char*)Ks + wb2)  = kreg1;                                             \
        *(uint4*)((char*)Vts + wb)  = vreg0;                                             \
        *(uint4*)((char*)Vts + wb2) = vreg1;                                             \
    } while (0)

    floatx4 o[4][2] = {};              // O^T[d=dt*16+quad*4+r][q=nf*16+l16]
    float l_i[2] = {0.f, 0.f};

    // prologue: tile 0 loaded + written
    LOAD_TILE(kt0);
    WRITE_TILE();
    __syncthreads();

    for (int it = 0; it < 16; ++it) {
        if (it + 1 < 16) LOAD_TILE(kt0 + (it + 1) * 64);   // issue-early (T14)

        // S^T[key][q] = K @ Q^T, kf read inline from swizzled Ks
        floatx4 s[4][2] = {};
#pragma unroll
        for (int ds = 0; ds < 2; ++ds)
#pragma unroll
            for (int jt = 0; jt < 4; ++jt) {
                const int p = (jt*16 + l16) * 128 + ds*64 + quad*16;
                const bf16x8 kf = *(const bf16x8*)((const char*)Ks + SWZA(p));
                s[jt][0] = __builtin_amdgcn_mfma_f32_16x16x32_bf16(kf, qf[0][ds], s[jt][0], 0, 0, 0);
                s[jt][1] = __builtin_amdgcn_mfma_f32_16x16x32_bf16(kf, qf[1][ds], s[jt][1], 0, 0, 0);
            }

        // p = exp2(s); per-lane l accumulation; pack to bf16 via v_perm
#pragma unroll
        for (int nf = 0; nf < 2; ++nf)
#pragma unroll
            for (int jt = 0; jt < 4; ++jt) {
                const float p0 = exp2f(s[jt][nf][0]);
                const float p1 = exp2f(s[jt][nf][1]);
                const float p2 = exp2f(s[jt][nf][2]);
                const float p3 = exp2f(s[jt][nf][3]);
                l_i[nf] += (p0 + p1) + (p2 + p3);
                uint2 pk;
                pk.x = __builtin_amdgcn_perm(fbits(p1), fbits(p0), 0x07060302u);
                pk.y = __builtin_amdgcn_perm(fbits(p3), fbits(p2), 0x07060302u);
                const int q = nf*16 + l16;
                const int kb = jt*32 + quad*8;
                *(uint2*)((char*)Ps[w] + q*128 + (kb ^ ((q & 7) << 4))) = pk;
            }

        // O^T += V^T @ P^T
#pragma unroll
        for (int kk = 0; kk < 2; ++kk) {
            const int cbyte = kk*64 + quad*16;
            const bf16x8 pf0 = *(const bf16x8*)((const char*)Ps[w] + l16*128      + (cbyte ^ ((l16 & 7) << 4)));
            const bf16x8 pf1 = *(const bf16x8*)((const char*)Ps[w] + (16+l16)*128 + (cbyte ^ ((l16 & 7) << 4)));
#pragma unroll
            for (int dt = 0; dt < 4; ++dt) {
                const int p = (dt*16 + l16) * 128 + cbyte;
                const bf16x8 vf = *(const bf16x8*)((const char*)Vts + SWZA(p));
                o[dt][0] = __builtin_amdgcn_mfma_f32_16x16x32_bf16(vf, pf0, o[dt][0], 0, 0, 0);
                o[dt][1] = __builtin_amdgcn_mfma_f32_16x16x32_bf16(vf, pf1, o[dt][1], 0, 0, 0);
            }
        }

        __syncthreads();                     // all waves done reading Ks/Vts
        if (it + 1 < 16) WRITE_TILE();       // vmcnt auto-inserted for regs
        __syncthreads();                     // writes visible to all waves
    }

    unsigned short* Op = Opart + (size_t)ks * ROWS * DIM;
#pragma unroll
    for (int nf = 0; nf < 2; ++nf) {
        float l = l_i[nf];
        l += __shfl_xor(l, 16, 64);
        l += __shfl_xor(l, 32, 64);
        const int q = q_base + nf*16 + l16;
        if (quad == 0)
            Lpart[((size_t)ks * 32 + bh) * L_SEQ + q] = l;
#pragma unroll
        for (int dt = 0; dt < 4; ++dt) {
            ushort4 ov;
            ov.x = f2bf(o[dt][nf][0]); ov.y = f2bf(o[dt][nf][1]);
            ov.z = f2bf(o[dt][nf][2]); ov.w = f2bf(o[dt][nf][3]);
            *(ushort4*)(Op + (size_t)(q * BATCH + b) * DIM + h * HDIM + dt*16 + quad*4) = ov;
        }
    }
#undef LOAD_TILE
#undef WRITE_TILE
}

// ---------------------------------------------------------------------------
// Merge: aw[row][col] = (O0+O1) / (l0+l1), bf16. One block per row.
// ---------------------------------------------------------------------------
__global__ __launch_bounds__(256)
void attn_merge(const unsigned short* __restrict__ Opart,
                const float* __restrict__ Lpart,
                unsigned short* __restrict__ Aout)
{
    const int row = blockIdx.x;           // 0..4095 (= q*BATCH + b)
    const int q = row >> 1, b = row & 1;
    const int t = threadIdx.x;
    const int col = t * 4;
    const int h = col >> 6;
    const int bh = b * 16 + h;
    const float l0 = Lpart[(size_t)bh * L_SEQ + q];
    const float l1 = Lpart[((size_t)32 + bh) * L_SEQ + q];
    const float inv = 1.0f / (l0 + l1);
    const ushort4 o0 = *(const ushort4*)(Opart + (size_t)row * DIM + col);
    const ushort4 o1 = *(const ushort4*)(Opart + (size_t)ROWS * DIM + (size_t)row * DIM + col);
    ushort4 ov;
    ov.x = f2bf((bf2f(o0.x) + bf2f(o1.x)) * inv);
    ov.y = f2bf((bf2f(o0.y) + bf2f(o1.y)) * inv);
    ov.z = f2bf((bf2f(o0.z) + bf2f(o1.z)) * inv);
    ov.w = f2bf((bf2f(o0.w) + bf2f(o1.w)) * inv);
    *(ushort4*)(Aout + (size_t)row * DIM + col) = ov;
}

// ---------------------------------------------------------------------------
// Launch
// ---------------------------------------------------------------------------
extern "C" void kernel_launch(void* const* d_in, const int* in_sizes, int n_in,
                              void* d_out, int out_size, void* d_ws, size_t ws_size,
                              hipStream_t stream)
{
    const float* x      = (const float*)d_in[0];
    const float* ln1_g  = (const float*)d_in[1];
    const float* ln1_b  = (const float*)d_in[2];
    const float* w_attn = (const float*)d_in[3];
    const float* b_attn = (const float*)d_in[4];
    const float* w_proj = (const float*)d_in[5];
    const float* b_proj = (const float*)d_in[6];
    const float* ln2_g  = (const float*)d_in[7];
    const float* ln2_b  = (const float*)d_in[8];
    const float* w_fc   = (const float*)d_in[9];
    const float* b_fc   = (const float*)d_in[10];
    const float* w_out  = (const float*)d_in[11];
    const float* b_out  = (const float*)d_in[12];

    char* ws = (char*)d_ws;
    unsigned short* watT   = (unsigned short*)(ws + 0);           // [3072,1024] bf16
    unsigned short* wprojT = (unsigned short*)(ws + 6291456);     // [1024,1024]
    unsigned short* wfcT   = (unsigned short*)(ws + 8388608);     // [4096,1024]
    unsigned short* woutT  = (unsigned short*)(ws + 16777216);    // [1024,4096]
    unsigned short* h      = (unsigned short*)(ws + 25165824);    // [4096,1024]
    unsigned short* qkv    = (unsigned short*)(ws + 33554432);    // [4096,3072]
    // After split/transpose_v, qkv region is dead -> reuse for attn partials:
    unsigned short* opart  = (unsigned short*)(ws + 33554432);    // [2][4096][1024] bf16 (16MB)
    float*          lpart  = (float*)(ws + 50331648);             // [2][32][2048] fp32 (512KB)
    unsigned short* mws    = (unsigned short*)(ws + 33554432);    // [4096,4096] (reuses region later)
    unsigned short* qw     = (unsigned short*)(ws + 58720256);    // [32,2048,64]
    unsigned short* kw     = (unsigned short*)(ws + 67108864);    // [32,2048,64]
    unsigned short* vt     = (unsigned short*)(ws + 75497472);    // [32,64,2048] (transposed V)
    unsigned short* aw     = (unsigned short*)(ws + 83886080);    // [4096,1024]
    unsigned short* x2     = (unsigned short*)(ws + 92274688);    // [4096,1024] bf16 residual stream
    // split-K partial for the out GEMM: 16MB fp32, reuses vt+aw (dead at step 9)
    float*          kpart  = (float*)(ws + 75497472);             // [4096,1024] fp32

    float* xout    = (float*)d_out;                // [2048,2,1024]
    float* present = (float*)d_out + 4194304;      // [2,2,16,2048,64]

    // 1. all weight transposes (fp32 -> bf16 [N,K])
    transpose_all<<<12288, 256, 0, stream>>>(w_attn, watT, w_proj, wprojT, w_fc, wfcT, w_out, woutT);

    // 2. LN1
    ln_rows<0><<<ROWS, 256, 0, stream>>>(x, ln1_g, ln1_b, h);
    // 3. QKV GEMM -> bf16 (256^2 deep-pipelined v2, 16x12 = 192 blocks)
    gemm256b<0,1><<<dim3(192), 512, 0, stream>>>(h, watT, b_attn, qkv, ROWS, 3*DIM, DIM, 16);
    // 4. split (q scaled, k, present-K) + V transpose (+present-V)
    split_qkv<<<4096, 256, 0, stream>>>(qkv, qw, kw, present);
    transpose_v<<<dim3(32, 32), 256, 0, stream>>>(qkv, vt, present);
    // 5. attention v3 (key-split x2 -> 1024 blocks, 4/CU) + merge
    attn_kernel<<<dim3(16, 2, 32), 256, 0, stream>>>(qw, kw, vt, opart, lpart);
    attn_merge<<<ROWS, 256, 0, stream>>>(opart, lpart, aw);
    // 6. proj + residual -> x2 bf16 (64x128 tiles: 512 blocks)
    gemm_bt<0,1,1,2,1><<<dim3(64, 8), 256, 0, stream>>>(aw, wprojT, b_proj, x, x2, nullptr, ROWS, DIM, DIM);
    // 7. LN2 (bf16 input)
    ln_rows<1><<<ROWS, 256, 0, stream>>>(x2, ln2_g, ln2_b, h);
    // 8. FC + GELU -> bf16 (256^2 deep-pipelined v2, 16x16 = 256 blocks)
    gemm256b<1,1><<<dim3(256), 512, 0, stream>>>(h, wfcT, b_fc, mws, ROWS, DFF_, DIM, 16);
    // 9. out GEMM, 128x128 tile + split-K 2 (grid 32x8x2 = 512 blocks, 2/CU)
    //    — R5-proven deterministic path (atomic experiment shelved pending
    //    a clean bench after the R6 infra failure).
    gemm_bt<0,2,0,4,2><<<dim3(32, 8, 2), 256, 0, stream>>>(mws, woutT, b_out, x2, xout, kpart, ROWS, DIM, DFF_);
    splitk_add<<<4096, 256, 0, stream>>>(kpart, xout);
}